// Round 1
// baseline (7321.365 us; speedup 1.0000x reference)
//
#include <hip/hip_runtime.h>

// ============================================================================
// Bidirectional LSTM (Keras-style), B=64 T=256 I=512 H=800, fp32 in/out.
// Strategy:
//   K0  pack W/U -> bf16 MFMA B-fragment layout (coalesced 16B/lane loads)
//   K1  all input projections (both dirs, bias folded) via mfma_f32_16x16x32_bf16
//       proj_f stored bf16 ALIASED into d_out Hcat region (same 104.86MB size);
//       Hcat row s is only written at step s+1 (delayed) -> no overlap with
//       proj_f row s which is consumed at step s.
//   K2  x256: one launch per timestep; 100 single-wave blocks, each owns
//       (dir, 16-j tile) x all 64 batches x all 4 gates -> gate combine fully
//       in-registers, no barriers. h ping-pong in ws (bf16 for GEMM + fp32).
//   K3  final Hcat row + hcat + ccat.
// ============================================================================

#define BDIM 64
#define TDIM 256
#define IDIM 512
#define HDIM 800
#define H4   3200

typedef __bf16 bf16;
typedef __bf16 bf16x8 __attribute__((ext_vector_type(8)));
typedef float  f32x4  __attribute__((ext_vector_type(4)));

// workspace layout (bytes)
#define OFF_UPK   0u            // 2*200*25*512 bf16 = 10,240,000
#define OFF_WPK   10240000u     // 2*200*16*512 bf16 =  6,553,600
#define OFF_PROJB 16793600u     // 64*256*3200 bf16  = 104,857,600
#define OFF_HBF   121651200u    // 2 bufs * 2*64*800 bf16 = 409,600
#define OFF_HF32  122060800u    // 2 bufs * 2*64*800 f32  = 819,200
#define OFF_C     122880000u    // 2*64*800 f32 = 409,600
#define WS_NEED   123289600u

__device__ __forceinline__ float sigf(float x)   { return 1.0f / (1.0f + __expf(-x)); }
__device__ __forceinline__ float tanhf_f(float x){ return 2.0f / (1.0f + __expf(-2.0f*x)) - 1.0f; }

// ---------------------------------------------------------------------------
// zero-init h (bf16+f32, both buffers) and c: 1,638,400 B = 102,400 uint4
__global__ __launch_bounds__(256) void kinit(uint4* __restrict__ p) {
    p[(size_t)blockIdx.x * 256 + threadIdx.x] = uint4{0u, 0u, 0u, 0u};
}

// ---------------------------------------------------------------------------
// pack fp32 [K][3200] weights into bf16 B-fragment tiles:
// tile (d, nt, kt): lane l holds S[kt*32 + (l>>4)*8 + j][nt*16 + (l&15)], j=0..7
__global__ __launch_bounds__(64) void kpack(const float* __restrict__ Sf,
                                            const float* __restrict__ Sb,
                                            bf16* __restrict__ dst, int nkt) {
    int bx = blockIdx.x;
    int kt = bx % nkt; int rest = bx / nkt;
    int nt = rest % 200; int d = rest / 200;
    const float* S = d ? Sb : Sf;
    int l  = threadIdx.x;
    int n  = nt * 16 + (l & 15);
    int k0 = kt * 32 + (l >> 4) * 8;
    bf16x8 v;
#pragma unroll
    for (int j = 0; j < 8; ++j) v[j] = (bf16)S[(size_t)(k0 + j) * H4 + n];
    *(bf16x8*)(dst + ((size_t)bx * 64 + l) * 8) = v;
}

// ---------------------------------------------------------------------------
// K1: proj[d][b][s][g*800+j] = sum_i x[b, t_eff, i]*mask[b,g,i]*W[i,g*800+j] + bias
// t_eff = s (fwd) or 255-s (bwd).  grid: d*5120 + b*80 + g*20 + tt*5 + jj
#define K1ROW 520   // 512 + 8 pad (bank decorrelation)
__global__ __launch_bounds__(256, 1) void kproj(
    const float* __restrict__ x, const float* __restrict__ mf, const float* __restrict__ mb,
    const bf16* __restrict__ wpk, const float* __restrict__ biasf, const float* __restrict__ biasb,
    bf16* __restrict__ projf, bf16* __restrict__ projb) {
    __shared__ bf16 sA[64 * K1ROW];   // 66,560 B

    int bx = blockIdx.x;
    int jj = bx % 5; int tt = (bx / 5) & 3; int g = (bx / 20) & 3;
    int b  = (bx / 80) & 63; int d = bx / 5120;

    int t  = threadIdx.x;
    int wv = t >> 6, l = t & 63;

    const float* mask = (d ? mb : mf) + (size_t)(b * 4 + g) * IDIM;
    int k = l * 8;
    float4 m0 = *(const float4*)(mask + k);
    float4 m1 = *(const float4*)(mask + k + 4);

    // stage masked-x tile: wave-iteration = one full row (coalesced 2KB read)
    for (int it = 0; it < 16; ++it) {
        int trow = it * 4 + wv;
        int tg   = tt * 64 + trow;
        int te   = d ? (255 - tg) : tg;
        const float* xs = x + ((size_t)b * TDIM + te) * IDIM + k;
        float4 x0 = *(const float4*)xs;
        float4 x1 = *(const float4*)(xs + 4);
        bf16x8 v;
        v[0] = (bf16)(x0.x * m0.x); v[1] = (bf16)(x0.y * m0.y);
        v[2] = (bf16)(x0.z * m0.z); v[3] = (bf16)(x0.w * m0.w);
        v[4] = (bf16)(x1.x * m1.x); v[5] = (bf16)(x1.y * m1.y);
        v[6] = (bf16)(x1.z * m1.z); v[7] = (bf16)(x1.w * m1.w);
        *(bf16x8*)(&sA[trow * K1ROW + k]) = v;
    }
    __syncthreads();

    f32x4 acc[10];
#pragma unroll
    for (int nt = 0; nt < 10; ++nt) acc[nt] = f32x4{0.f, 0.f, 0.f, 0.f};

    int NTbase = g * 50 + jj * 10;
    const bf16* wb = wpk + ((size_t)d * 200 + NTbase) * 16 * 512 + l * 8;
    for (int kt = 0; kt < 16; ++kt) {
        bf16x8 a = *(const bf16x8*)(&sA[(wv * 16 + (l & 15)) * K1ROW + kt * 32 + (l >> 4) * 8]);
#pragma unroll
        for (int nt = 0; nt < 10; ++nt) {
            bf16x8 bw = *(const bf16x8*)(wb + ((size_t)nt * 16 + kt) * 512);
            acc[nt] = __builtin_amdgcn_mfma_f32_16x16x32_bf16(a, bw, acc[nt], 0, 0, 0);
        }
    }

    const float* bias = d ? biasb : biasf;
    bf16* dst = d ? projb : projf;
    int row0 = tt * 64 + wv * 16 + ((l >> 4) * 4);
    int colb = g * HDIM + jj * 160 + (l & 15);
#pragma unroll
    for (int nt = 0; nt < 10; ++nt) {
        int col = colb + nt * 16;
        float bv = bias[col];
#pragma unroll
        for (int r = 0; r < 4; ++r) {
            int trow = row0 + r;
            dst[((size_t)b * TDIM + trow) * H4 + col] = (bf16)(acc[nt][r] + bv);
        }
    }
}

// ---------------------------------------------------------------------------
// K2: one timestep. grid = 100 blocks x 64 thr (d = bx/50, jt = bx%50).
// Wave owns (d, j0..j0+15) x all 64 b x all 4 gates.
__global__ __launch_bounds__(64, 1) void kstep(
    const bf16* __restrict__ upk,
    const bf16* __restrict__ projf, const bf16* __restrict__ projb,
    const bf16* __restrict__ hin, bf16* __restrict__ hout,
    const float* __restrict__ hfin, float* __restrict__ hfout,
    float* __restrict__ cws, float* __restrict__ out, int s) {
    __shared__ uint4 spr[512];   // proj tile: [b][g][16 j] bf16 = 8KB

    int bx = blockIdx.x;
    int jt = bx % 50; int d = bx / 50;
    int l  = threadIdx.x;
    int j0 = jt * 16;

    const char* prbase = (const char*)(d ? projb : projf);
#pragma unroll
    for (int i = 0; i < 8; ++i) {
        int id = i * 64 + l;                 // (b, g, half)
        int c16 = id & 1; int g = (id >> 1) & 3; int b = id >> 3;
        spr[id] = *(const uint4*)(prbase + (size_t)(b * 256 + s) * 6400
                                         + (size_t)(g * HDIM + j0) * 2 + c16 * 16);
    }
    __syncthreads();

    f32x4 acc[4][4];   // [gate][m-tile]
#pragma unroll
    for (int g = 0; g < 4; ++g)
#pragma unroll
        for (int mt = 0; mt < 4; ++mt) acc[g][mt] = f32x4{0.f, 0.f, 0.f, 0.f};

    const bf16* hbase = hin + (size_t)d * 64 * HDIM;
    const bf16* ub = upk + ((size_t)d * 200 + jt) * 25 * 512 + l * 8;
    int lm = l & 15, q = l >> 4;
    for (int kt = 0; kt < 25; ++kt) {
        bf16x8 a[4];
#pragma unroll
        for (int mt = 0; mt < 4; ++mt)
            a[mt] = *(const bf16x8*)(hbase + (size_t)(mt * 16 + lm) * HDIM + kt * 32 + q * 8);
#pragma unroll
        for (int g = 0; g < 4; ++g) {
            bf16x8 bw = *(const bf16x8*)(ub + ((size_t)g * 1250 + kt) * 512);
#pragma unroll
            for (int mt = 0; mt < 4; ++mt)
                acc[g][mt] = __builtin_amdgcn_mfma_f32_16x16x32_bf16(a[mt], bw, acc[g][mt], 0, 0, 0);
        }
    }

    const bf16* sp = (const bf16*)spr;
    int jcol = j0 + lm;
#pragma unroll
    for (int mt = 0; mt < 4; ++mt) {
#pragma unroll
        for (int r = 0; r < 4; ++r) {
            int b = mt * 16 + q * 4 + r;
            float zi = acc[0][mt][r] + (float)sp[(b * 4 + 0) * 16 + lm];
            float zf = acc[1][mt][r] + (float)sp[(b * 4 + 1) * 16 + lm];
            float zg = acc[2][mt][r] + (float)sp[(b * 4 + 2) * 16 + lm];
            float zo = acc[3][mt][r] + (float)sp[(b * 4 + 3) * 16 + lm];
            float ig = sigf(zi), fg = sigf(zf), gg = tanhf_f(zg), og = sigf(zo);
            size_t ci = (size_t)(d * 64 + b) * HDIM + jcol;
            float cn = fg * cws[ci] + ig * gg;
            cws[ci] = cn;
            float h = og * tanhf_f(cn);
            hout[ci]  = (bf16)h;
            hfout[ci] = h;
        }
    }

    // delayed Hcat write: h of step s-1 (avoids aliasing race with proj_f in d_out)
    if (s > 0) {
#pragma unroll
        for (int mt = 0; mt < 4; ++mt)
#pragma unroll
            for (int r = 0; r < 4; ++r) {
                int b = mt * 16 + q * 4 + r;
                out[((size_t)b * TDIM + (s - 1)) * 1600 + d * HDIM + jcol] =
                    hfin[(size_t)(d * 64 + b) * HDIM + jcol];
            }
    }
}

// ---------------------------------------------------------------------------
// K3: Hcat row 255 + hcat + ccat
__global__ __launch_bounds__(256) void kfinal(const float* __restrict__ hf0,
                                              const float* __restrict__ cws,
                                              float* __restrict__ out) {
    int idx = blockIdx.x * 256 + threadIdx.x;       // 102,400 = d*51200 + b*800 + j
    int j = idx % HDIM; int b = (idx / HDIM) & 63; int d = idx / (HDIM * 64);
    float h = hf0[idx];
    float c = cws[idx];
    out[((size_t)b * TDIM + 255) * 1600 + d * HDIM + j] = h;
    out[26214400u + (size_t)b * 1600 + d * HDIM + j] = h;
    out[26316800u + (size_t)b * 1600 + d * HDIM + j] = c;
}

// ---------------------------------------------------------------------------
extern "C" void kernel_launch(void* const* d_in, const int* in_sizes, int n_in,
                              void* d_out, int out_size, void* d_ws, size_t ws_size,
                              hipStream_t stream) {
    const float* x   = (const float*)d_in[0];
    const float* mf  = (const float*)d_in[1];
    const float* mb  = (const float*)d_in[2];
    const float* Wf  = (const float*)d_in[3];
    const float* Uf  = (const float*)d_in[4];
    const float* bf_ = (const float*)d_in[5];
    const float* Wb  = (const float*)d_in[6];
    const float* Ub  = (const float*)d_in[7];
    const float* bb_ = (const float*)d_in[8];

    if (ws_size < (size_t)WS_NEED) return;   // clean failure signal if ws too small

    char*  ws    = (char*)d_ws;
    bf16*  upk   = (bf16*)(ws + OFF_UPK);
    bf16*  wpk   = (bf16*)(ws + OFF_WPK);
    bf16*  projb = (bf16*)(ws + OFF_PROJB);
    bf16*  hbf   = (bf16*)(ws + OFF_HBF);
    float* hf32  = (float*)(ws + OFF_HF32);
    float* cws   = (float*)(ws + OFF_C);
    float* out   = (float*)d_out;
    bf16*  projf = (bf16*)d_out;    // fwd proj aliased into Hcat region (same size)

    kinit<<<400, 256, 0, stream>>>((uint4*)(ws + OFF_HBF));
    kpack<<<10000, 64, 0, stream>>>(Uf, Ub, upk, 25);
    kpack<<<6400, 64, 0, stream>>>(Wf, Wb, wpk, 16);
    kproj<<<10240, 256, 0, stream>>>(x, mf, mb, wpk, bf_, bb_, projf, projb);

    for (int s = 0; s < 256; ++s) {
        const bf16*  hin   = hbf  + (size_t)(s & 1) * 102400;
        bf16*        houtp = hbf  + (size_t)((s + 1) & 1) * 102400;
        const float* hfin  = hf32 + (size_t)(s & 1) * 102400;
        float*       hfoutp= hf32 + (size_t)((s + 1) & 1) * 102400;
        kstep<<<100, 64, 0, stream>>>(upk, projf, projb, hin, houtp, hfin, hfoutp,
                                      cws, out, s);
    }
    kfinal<<<400, 256, 0, stream>>>(hf32, cws, out);
}

// Round 2
// 6953.423 us; speedup vs baseline: 1.0529x; 1.0529x over previous
//
#include <hip/hip_runtime.h>

// ============================================================================
// Bidirectional LSTM (Keras-style), B=64 T=256 I=512 H=800, fp32 in/out.
//   K0  pack W/U -> bf16 MFMA B-fragment layout
//   K1  kproj: all input projections (both dirs, bias folded), bf16 MFMA;
//       proj_f ALIASED into d_out Hcat region (same 104.86MB); Hcat row s
//       written only after all blocks consumed proj row s (barrier-ordered).
//   K2  krecur: ONE persistent kernel, 100 single-wave blocks (d x 16-j tile),
//       256 steps with device-scope flag barrier. c and fp32-h live in
//       registers; only bf16 h ping-pongs through global for the GEMM.
// ============================================================================

#define BDIM 64
#define TDIM 256
#define IDIM 512
#define HDIM 800
#define H4   3200

typedef __bf16 bf16;
typedef __bf16 bf16x8 __attribute__((ext_vector_type(8)));
typedef float  f32x4  __attribute__((ext_vector_type(4)));

// workspace layout (bytes)
#define OFF_UPK   0u            // 2*200*25*512 bf16 = 10,240,000
#define OFF_WPK   10240000u     // 2*200*16*512 bf16 =  6,553,600
#define OFF_PROJB 16793600u     // 64*256*3200 bf16  = 104,857,600
#define OFF_HBF   121651200u    // 2 bufs * 2*64*800 bf16 = 409,600
#define OFF_FLAGS 122060800u    // 100 * 128 B = 12,800
#define WS_NEED   122073600u

__device__ __forceinline__ float sigf(float x)   { return 1.0f / (1.0f + __expf(-x)); }
__device__ __forceinline__ float tanhf_f(float x){ return 2.0f / (1.0f + __expf(-2.0f*x)) - 1.0f; }

// ---------------------------------------------------------------------------
// zero-init h bf16 ping-pong buffers + barrier flags: 422,400 B = 26,400 uint4
__global__ __launch_bounds__(256) void kinit(uint4* __restrict__ p) {
    int idx = blockIdx.x * 256 + threadIdx.x;
    if (idx < 26400) p[idx] = uint4{0u, 0u, 0u, 0u};
}

// ---------------------------------------------------------------------------
// pack fp32 [K][3200] weights into bf16 B-fragment tiles:
// tile (d, nt, kt): lane l holds S[kt*32 + (l>>4)*8 + j][nt*16 + (l&15)], j=0..7
__global__ __launch_bounds__(64) void kpack(const float* __restrict__ Sf,
                                            const float* __restrict__ Sb,
                                            bf16* __restrict__ dst, int nkt) {
    int bx = blockIdx.x;
    int kt = bx % nkt; int rest = bx / nkt;
    int nt = rest % 200; int d = rest / 200;
    const float* S = d ? Sb : Sf;
    int l  = threadIdx.x;
    int n  = nt * 16 + (l & 15);
    int k0 = kt * 32 + (l >> 4) * 8;
    bf16x8 v;
#pragma unroll
    for (int j = 0; j < 8; ++j) v[j] = (bf16)S[(size_t)(k0 + j) * H4 + n];
    *(bf16x8*)(dst + ((size_t)bx * 64 + l) * 8) = v;
}

// ---------------------------------------------------------------------------
// K1: proj[d][b][s][g*800+j] = sum_i x[b,t_eff,i]*mask[b,g,i]*W[i,g*800+j] + b
// t_eff = s (fwd) or 255-s (bwd).  grid: d*5120 + b*80 + g*20 + tt*5 + jj
#define K1ROW 520   // 512 + 8 pad
__global__ __launch_bounds__(256, 1) void kproj(
    const float* __restrict__ x, const float* __restrict__ mf, const float* __restrict__ mb,
    const bf16* __restrict__ wpk, const float* __restrict__ biasf, const float* __restrict__ biasb,
    bf16* __restrict__ projf, bf16* __restrict__ projb) {
    __shared__ bf16 sA[64 * K1ROW];

    int bx = blockIdx.x;
    int jj = bx % 5; int tt = (bx / 5) & 3; int g = (bx / 20) & 3;
    int b  = (bx / 80) & 63; int d = bx / 5120;

    int t  = threadIdx.x;
    int wv = t >> 6, l = t & 63;

    const float* mask = (d ? mb : mf) + (size_t)(b * 4 + g) * IDIM;
    int k = l * 8;
    float4 m0 = *(const float4*)(mask + k);
    float4 m1 = *(const float4*)(mask + k + 4);

    for (int it = 0; it < 16; ++it) {
        int trow = it * 4 + wv;
        int tg   = tt * 64 + trow;
        int te   = d ? (255 - tg) : tg;
        const float* xs = x + ((size_t)b * TDIM + te) * IDIM + k;
        float4 x0 = *(const float4*)xs;
        float4 x1 = *(const float4*)(xs + 4);
        bf16x8 v;
        v[0] = (bf16)(x0.x * m0.x); v[1] = (bf16)(x0.y * m0.y);
        v[2] = (bf16)(x0.z * m0.z); v[3] = (bf16)(x0.w * m0.w);
        v[4] = (bf16)(x1.x * m1.x); v[5] = (bf16)(x1.y * m1.y);
        v[6] = (bf16)(x1.z * m1.z); v[7] = (bf16)(x1.w * m1.w);
        *(bf16x8*)(&sA[trow * K1ROW + k]) = v;
    }
    __syncthreads();

    f32x4 acc[10];
#pragma unroll
    for (int nt = 0; nt < 10; ++nt) acc[nt] = f32x4{0.f, 0.f, 0.f, 0.f};

    int NTbase = g * 50 + jj * 10;
    const bf16* wb = wpk + ((size_t)d * 200 + NTbase) * 16 * 512 + l * 8;
    for (int kt = 0; kt < 16; ++kt) {
        bf16x8 a = *(const bf16x8*)(&sA[(wv * 16 + (l & 15)) * K1ROW + kt * 32 + (l >> 4) * 8]);
#pragma unroll
        for (int nt = 0; nt < 10; ++nt) {
            bf16x8 bw = *(const bf16x8*)(wb + ((size_t)nt * 16 + kt) * 512);
            acc[nt] = __builtin_amdgcn_mfma_f32_16x16x32_bf16(a, bw, acc[nt], 0, 0, 0);
        }
    }

    const float* bias = d ? biasb : biasf;
    bf16* dst = d ? projb : projf;
    int row0 = tt * 64 + wv * 16 + ((l >> 4) * 4);
    int colb = g * HDIM + jj * 160 + (l & 15);
#pragma unroll
    for (int nt = 0; nt < 10; ++nt) {
        int col = colb + nt * 16;
        float bv = bias[col];
#pragma unroll
        for (int r = 0; r < 4; ++r) {
            int trow = row0 + r;
            dst[((size_t)b * TDIM + trow) * H4 + col] = (bf16)(acc[nt][r] + bv);
        }
    }
}

// ---------------------------------------------------------------------------
// K2: persistent recurrence. grid = 100 x 64 (d = bx/50, jt = bx%50).
// Wave owns (d, j0..j0+15) x all 64 b x all 4 gates across all 256 steps.
__global__ __launch_bounds__(64, 1) void krecur(
    const bf16* __restrict__ upk,
    const bf16* __restrict__ projf, const bf16* __restrict__ projb,
    bf16* __restrict__ hbf, int* __restrict__ flags,
    float* __restrict__ out) {
    __shared__ uint4 spr[512];   // proj tile: [b][g][16 j] bf16 = 8KB

    int bx = blockIdx.x;
    int jt = bx % 50; int d = bx / 50;
    int l  = threadIdx.x;
    int j0 = jt * 16;
    int lm = l & 15, q = l >> 4;
    int jcol = j0 + lm;

    const char* prbase = (const char*)(d ? projb : projf);
    const bf16* ub = upk + ((size_t)d * 200 + jt) * 25 * 512 + (size_t)l * 8;

    // flag poll mapping: lane l polls flags f1 and f2 (covers 0..99)
    int f1 = l;
    int f2 = (l < 36) ? (64 + l) : l;

    float hprev[4][4];   // fp32 h state, rows b = mt*16+q*4+r, col jcol
    float cst[4][4];     // c state
#pragma unroll
    for (int mt = 0; mt < 4; ++mt)
#pragma unroll
        for (int r = 0; r < 4; ++r) { hprev[mt][r] = 0.f; cst[mt][r] = 0.f; }

#pragma unroll 1
    for (int s = 0; s < 256; ++s) {
        // prefetch proj(s) into registers (no barrier dependency; drains in
        // our release fence before we signal s+1, so no race with Hcat(s))
        uint4 pr[8];
#pragma unroll
        for (int i = 0; i < 8; ++i) {
            int id = i * 64 + l;
            int c16 = id & 1; int g = (id >> 1) & 3; int b = id >> 3;
            pr[i] = *(const uint4*)(prbase + (size_t)(b * 256 + s) * 6400
                                           + (size_t)(g * HDIM + j0) * 2 + c16 * 16);
        }

        if (s > 0) {
            // wait for all blocks to finish step s-1
            for (;;) {
                int a  = __hip_atomic_load(flags + f1 * 32, __ATOMIC_RELAXED, __HIP_MEMORY_SCOPE_AGENT);
                int b2 = __hip_atomic_load(flags + f2 * 32, __ATOMIC_RELAXED, __HIP_MEMORY_SCOPE_AGENT);
                if (__all((a >= s) && (b2 >= s))) break;
            }
            __builtin_amdgcn_fence(__ATOMIC_ACQUIRE, "agent");
            // delayed Hcat write: row s-1 (all blocks have consumed proj(s-1))
#pragma unroll
            for (int mt = 0; mt < 4; ++mt)
#pragma unroll
                for (int r = 0; r < 4; ++r) {
                    int b = mt * 16 + q * 4 + r;
                    out[((size_t)b * TDIM + (s - 1)) * 1600 + d * HDIM + jcol] = hprev[mt][r];
                }
        }

        // stage proj tile to LDS
#pragma unroll
        for (int i = 0; i < 8; ++i) spr[i * 64 + l] = pr[i];
        __syncthreads();

        const bf16* hin  = hbf + (size_t)(s & 1) * 102400 + (size_t)d * 51200;
        bf16*       hout = hbf + (size_t)((s + 1) & 1) * 102400 + (size_t)d * 51200;

        f32x4 acc[4][4];   // [gate][m-tile]
#pragma unroll
        for (int g = 0; g < 4; ++g)
#pragma unroll
            for (int mt = 0; mt < 4; ++mt) acc[g][mt] = f32x4{0.f, 0.f, 0.f, 0.f};

        for (int kt = 0; kt < 25; ++kt) {
            bf16x8 a[4];
#pragma unroll
            for (int mt = 0; mt < 4; ++mt)
                a[mt] = *(const bf16x8*)(hin + (size_t)(mt * 16 + lm) * HDIM + kt * 32 + q * 8);
#pragma unroll
            for (int g = 0; g < 4; ++g) {
                bf16x8 bw = *(const bf16x8*)(ub + ((size_t)g * 1250 + kt) * 512);
#pragma unroll
                for (int mt = 0; mt < 4; ++mt)
                    acc[g][mt] = __builtin_amdgcn_mfma_f32_16x16x32_bf16(a[mt], bw, acc[g][mt], 0, 0, 0);
            }
        }

        const bf16* sp = (const bf16*)spr;
#pragma unroll
        for (int mt = 0; mt < 4; ++mt) {
#pragma unroll
            for (int r = 0; r < 4; ++r) {
                int b = mt * 16 + q * 4 + r;
                float zi = acc[0][mt][r] + (float)sp[(b * 4 + 0) * 16 + lm];
                float zf = acc[1][mt][r] + (float)sp[(b * 4 + 1) * 16 + lm];
                float zg = acc[2][mt][r] + (float)sp[(b * 4 + 2) * 16 + lm];
                float zo = acc[3][mt][r] + (float)sp[(b * 4 + 3) * 16 + lm];
                float ig = sigf(zi), fg = sigf(zf), gg = tanhf_f(zg), og = sigf(zo);
                float cn = fg * cst[mt][r] + ig * gg;
                cst[mt][r] = cn;
                float h = og * tanhf_f(cn);
                hprev[mt][r] = h;
                hout[(size_t)b * HDIM + jcol] = (bf16)h;
            }
        }
        __syncthreads();   // protect spr reuse next iteration

        // signal step s done (release: h + Hcat stores drained & visible)
        __builtin_amdgcn_fence(__ATOMIC_RELEASE, "agent");
        if (l == 0)
            __hip_atomic_store(flags + bx * 32, s + 1, __ATOMIC_RELAXED, __HIP_MEMORY_SCOPE_AGENT);
    }

    // terminal barrier: all blocks consumed proj(255) -> safe to overwrite
    for (;;) {
        int a  = __hip_atomic_load(flags + f1 * 32, __ATOMIC_RELAXED, __HIP_MEMORY_SCOPE_AGENT);
        int b2 = __hip_atomic_load(flags + f2 * 32, __ATOMIC_RELAXED, __HIP_MEMORY_SCOPE_AGENT);
        if (__all((a >= 256) && (b2 >= 256))) break;
    }
    __builtin_amdgcn_fence(__ATOMIC_ACQUIRE, "agent");

    // Hcat row 255 + hcat + ccat from registers
#pragma unroll
    for (int mt = 0; mt < 4; ++mt)
#pragma unroll
        for (int r = 0; r < 4; ++r) {
            int b = mt * 16 + q * 4 + r;
            out[((size_t)b * TDIM + 255) * 1600 + d * HDIM + jcol] = hprev[mt][r];
            out[26214400u + (size_t)b * 1600 + d * HDIM + jcol] = hprev[mt][r];
            out[26316800u + (size_t)b * 1600 + d * HDIM + jcol] = cst[mt][r];
        }
}

// ---------------------------------------------------------------------------
extern "C" void kernel_launch(void* const* d_in, const int* in_sizes, int n_in,
                              void* d_out, int out_size, void* d_ws, size_t ws_size,
                              hipStream_t stream) {
    const float* x   = (const float*)d_in[0];
    const float* mf  = (const float*)d_in[1];
    const float* mb  = (const float*)d_in[2];
    const float* Wf  = (const float*)d_in[3];
    const float* Uf  = (const float*)d_in[4];
    const float* bf_ = (const float*)d_in[5];
    const float* Wb  = (const float*)d_in[6];
    const float* Ub  = (const float*)d_in[7];
    const float* bb_ = (const float*)d_in[8];

    if (ws_size < (size_t)WS_NEED) return;

    char*  ws    = (char*)d_ws;
    bf16*  upk   = (bf16*)(ws + OFF_UPK);
    bf16*  wpk   = (bf16*)(ws + OFF_WPK);
    bf16*  projb = (bf16*)(ws + OFF_PROJB);
    bf16*  hbf   = (bf16*)(ws + OFF_HBF);
    int*   flags = (int*)(ws + OFF_FLAGS);
    float* out   = (float*)d_out;
    bf16*  projf = (bf16*)d_out;    // fwd proj aliased into Hcat region

    kinit<<<104, 256, 0, stream>>>((uint4*)(ws + OFF_HBF));
    kpack<<<10000, 64, 0, stream>>>(Uf, Ub, upk, 25);
    kpack<<<6400, 64, 0, stream>>>(Wf, Wb, wpk, 16);
    kproj<<<10240, 256, 0, stream>>>(x, mf, mb, wpk, bf_, bb_, projf, projb);
    krecur<<<100, 64, 0, stream>>>(upk, projf, projb, hbf, flags, out);
}

// Round 4
// 5379.029 us; speedup vs baseline: 1.3611x; 1.2927x over previous
//
#include <hip/hip_runtime.h>

// ============================================================================
// Bidirectional LSTM (Keras-style), B=64 T=256 I=512 H=800, fp32 in/out.
//   K0  pack W/U -> bf16 MFMA B-fragment layout
//   K1  kproj: input projections (both dirs, bias folded), bf16 MFMA, row
//       layout [b][t][j*4+g]; proj_f ALIASED into d_out Hcat region.
//   K2  krecur: ONE persistent kernel, 100 single-wave blocks, 256 steps.
//       NO agent fences: h written via sc1 (write-through to coherence point)
//       into a ROLLING 257-slot buffer (virgin addresses -> cached consumer
//       loads can never be stale -> no buffer_inv -> U stays L2-resident).
//       Flags via relaxed agent-scope atomics after s_waitcnt vmcnt(0).
// ============================================================================

#define TDIM 256
#define IDIM 512
#define HDIM 800
#define H4   3200

typedef __bf16 bf16;
typedef __bf16 bf16x8 __attribute__((ext_vector_type(8)));
typedef __bf16 bf16x4 __attribute__((ext_vector_type(4)));
typedef float  f32x4  __attribute__((ext_vector_type(4)));
typedef unsigned int u32x4 __attribute__((ext_vector_type(4)));

// workspace layout (bytes)
#define OFF_UPK   0ull            // 2*200*25*512 bf16 = 10,240,000
#define OFF_WPK   10240000ull     // 2*200*16*512 bf16 =  6,553,600
#define OFF_PROJB 16793600ull     // 64*256*3200 bf16  = 104,857,600
#define OFF_HA    121651200ull    // 257 slots * 204,800 B = 52,633,600
#define OFF_FLAGS 174284800ull    // 100 * 128 B = 12,800
#define WS_NEED   174297600ull

__device__ __forceinline__ float sigf(float x)   { return 1.0f / (1.0f + __expf(-x)); }
__device__ __forceinline__ float tanhf_f(float x){ return 2.0f / (1.0f + __expf(-2.0f*x)) - 1.0f; }

__device__ __forceinline__ void store_b128_sc1(void* p, u32x4 v) {
    asm volatile("global_store_dwordx4 %0, %1, off sc1" :: "v"(p), "v"(v) : "memory");
}

// ---------------------------------------------------------------------------
// zero-init hA slot 0 (12,800 uint4) + flags (800 uint4)
__global__ __launch_bounds__(256) void kinit(uint4* __restrict__ ha0,
                                             uint4* __restrict__ flg) {
    int idx = blockIdx.x * 256 + threadIdx.x;
    if (idx < 12800) ha0[idx] = uint4{0u, 0u, 0u, 0u};
    else if (idx < 13600) flg[idx - 12800] = uint4{0u, 0u, 0u, 0u};
}

// ---------------------------------------------------------------------------
// pack fp32 [K][3200] weights into bf16 B-fragment tiles:
// tile (d, nt, kt): lane l holds S[kt*32 + (l>>4)*8 + j][nt*16 + (l&15)], j=0..7
__global__ __launch_bounds__(64) void kpack(const float* __restrict__ Sf,
                                            const float* __restrict__ Sb,
                                            bf16* __restrict__ dst, int nkt) {
    int bx = blockIdx.x;
    int kt = bx % nkt; int rest = bx / nkt;
    int nt = rest % 200; int d = rest / 200;
    const float* S = d ? Sb : Sf;
    int l  = threadIdx.x;
    int n  = nt * 16 + (l & 15);
    int k0 = kt * 32 + (l >> 4) * 8;
    bf16x8 v;
#pragma unroll
    for (int j = 0; j < 8; ++j) v[j] = (bf16)S[(size_t)(k0 + j) * H4 + n];
    *(bf16x8*)(dst + ((size_t)bx * 64 + l) * 8) = v;
}

// ---------------------------------------------------------------------------
// K1: proj row layout [b][t][j*4 + g], j in [0,800), g in [0,4).
// t_eff = s (fwd) or 255-s (bwd).  grid: d*5120 + b*80 + g*20 + tt*5 + jj
#define K1ROW 520
__global__ __launch_bounds__(256, 1) void kproj(
    const float* __restrict__ x, const float* __restrict__ mf, const float* __restrict__ mb,
    const bf16* __restrict__ wpk, const float* __restrict__ biasf, const float* __restrict__ biasb,
    bf16* __restrict__ projf, bf16* __restrict__ projb) {
    __shared__ bf16 sA[64 * K1ROW];

    int bx = blockIdx.x;
    int jj = bx % 5; int tt = (bx / 5) & 3; int g = (bx / 20) & 3;
    int b  = (bx / 80) & 63; int d = bx / 5120;

    int t  = threadIdx.x;
    int wv = t >> 6, l = t & 63;

    const float* mask = (d ? mb : mf) + (size_t)(b * 4 + g) * IDIM;
    int k = l * 8;
    float4 m0 = *(const float4*)(mask + k);
    float4 m1 = *(const float4*)(mask + k + 4);

    for (int it = 0; it < 16; ++it) {
        int trow = it * 4 + wv;
        int tg   = tt * 64 + trow;
        int te   = d ? (255 - tg) : tg;
        const float* xs = x + ((size_t)b * TDIM + te) * IDIM + k;
        float4 x0 = *(const float4*)xs;
        float4 x1 = *(const float4*)(xs + 4);
        bf16x8 v;
        v[0] = (bf16)(x0.x * m0.x); v[1] = (bf16)(x0.y * m0.y);
        v[2] = (bf16)(x0.z * m0.z); v[3] = (bf16)(x0.w * m0.w);
        v[4] = (bf16)(x1.x * m1.x); v[5] = (bf16)(x1.y * m1.y);
        v[6] = (bf16)(x1.z * m1.z); v[7] = (bf16)(x1.w * m1.w);
        *(bf16x8*)(&sA[trow * K1ROW + k]) = v;
    }
    __syncthreads();

    f32x4 acc[10];
#pragma unroll
    for (int nt = 0; nt < 10; ++nt) acc[nt] = f32x4{0.f, 0.f, 0.f, 0.f};

    int NTbase = g * 50 + jj * 10;
    const bf16* wb = wpk + ((size_t)d * 200 + NTbase) * 16 * 512 + l * 8;
    for (int kt = 0; kt < 16; ++kt) {
        bf16x8 a = *(const bf16x8*)(&sA[(wv * 16 + (l & 15)) * K1ROW + kt * 32 + (l >> 4) * 8]);
#pragma unroll
        for (int nt = 0; nt < 10; ++nt) {
            bf16x8 bw = *(const bf16x8*)(wb + ((size_t)nt * 16 + kt) * 512);
            acc[nt] = __builtin_amdgcn_mfma_f32_16x16x32_bf16(a, bw, acc[nt], 0, 0, 0);
        }
    }

    const float* bias = d ? biasb : biasf;
    bf16* dst = d ? projb : projf;
    int row0 = tt * 64 + wv * 16 + ((l >> 4) * 4);
#pragma unroll
    for (int nt = 0; nt < 10; ++nt) {
        int jr = jj * 160 + nt * 16 + (l & 15);
        float bv = bias[g * HDIM + jr];
#pragma unroll
        for (int r = 0; r < 4; ++r) {
            int trow = row0 + r;
            dst[((size_t)b * TDIM + trow) * H4 + (size_t)jr * 4 + g] = (bf16)(acc[nt][r] + bv);
        }
    }
}

// ---------------------------------------------------------------------------
// K2: persistent recurrence. grid = 100 x 64 (d = bx/50, jt = bx%50).
// hA slot layout: [slot][d][kt(25)][mt(4)][lane(64)][8] bf16 (A-fragment packed)
__global__ __launch_bounds__(64, 1) void krecur(
    const bf16* __restrict__ upk,
    const bf16* __restrict__ projf, const bf16* __restrict__ projb,
    bf16* __restrict__ hA, int* __restrict__ flags,
    float* __restrict__ out) {
    __shared__ uint4 spr[64 * 9];   // proj tile [b][9 uint4] (8 used, +1 pad)
    __shared__ bf16  sh2[64 * 24];  // h transpose [b][24] (16 used, pad->16B align)

    int bx = blockIdx.x;
    int jt = bx % 50; int d = bx / 50;
    int l  = threadIdx.x;
    int j0 = jt * 16;
    int lm = l & 15, q = l >> 4;
    int jcol = j0 + lm;
    int kt0 = jt >> 1, qbase = (jt & 1) * 2;
    int qq = q & 1, mtsel = q >> 1;

    const char* prbase = (const char*)(d ? projb : projf);
    const bf16* ub = upk + ((size_t)d * 200 + jt) * 25 * 512 + (size_t)l * 8;

    int f1 = l;
    int f2 = (l < 36) ? (64 + l) : l;

    float hprev[4][4], cst[4][4];
#pragma unroll
    for (int mt = 0; mt < 4; ++mt)
#pragma unroll
        for (int r = 0; r < 4; ++r) { hprev[mt][r] = 0.f; cst[mt][r] = 0.f; }

#pragma unroll 1
    for (int s = 0; s < 256; ++s) {
        // prefetch proj(s): 128 B per b, interleaved [j][g] layout
        uint4 pr[8];
#pragma unroll
        for (int i = 0; i < 8; ++i) {
            int id = i * 64 + l;
            int b = id >> 3; int c = id & 7;
            pr[i] = *(const uint4*)(prbase + (size_t)(b * TDIM + s) * 6400
                                           + (size_t)j0 * 8 + (size_t)c * 16);
        }

        if (s > 0) {
            for (;;) {
                int a  = __hip_atomic_load(flags + f1 * 32, __ATOMIC_RELAXED, __HIP_MEMORY_SCOPE_AGENT);
                int b2 = __hip_atomic_load(flags + f2 * 32, __ATOMIC_RELAXED, __HIP_MEMORY_SCOPE_AGENT);
                if (__all((a >= s) && (b2 >= s))) break;
            }
            asm volatile("" ::: "memory");   // no HW fence needed: virgin addrs
            // delayed Hcat write: row s-1
#pragma unroll
            for (int mt = 0; mt < 4; ++mt)
#pragma unroll
                for (int r = 0; r < 4; ++r) {
                    int b = mt * 16 + q * 4 + r;
                    out[((size_t)b * TDIM + (s - 1)) * 1600 + d * HDIM + jcol] = hprev[mt][r];
                }
        }

        // stage proj tile to LDS (single wave -> no barrier needed)
#pragma unroll
        for (int i = 0; i < 8; ++i) {
            int id = i * 64 + l;
            spr[(id >> 3) * 9 + (id & 7)] = pr[i];
        }

        const bf16* hin = hA + (size_t)s * 102400 + (size_t)d * 51200 + (size_t)l * 8;

        f32x4 acc[4][4];
#pragma unroll
        for (int g = 0; g < 4; ++g)
#pragma unroll
            for (int mt = 0; mt < 4; ++mt) acc[g][mt] = f32x4{0.f, 0.f, 0.f, 0.f};

        for (int kt = 0; kt < 25; ++kt) {
            bf16x8 af[4];
#pragma unroll
            for (int mt = 0; mt < 4; ++mt)
                af[mt] = *(const bf16x8*)(hin + (size_t)(kt * 4 + mt) * 512);
#pragma unroll
            for (int g = 0; g < 4; ++g) {
                bf16x8 bw = *(const bf16x8*)(ub + ((size_t)g * 1250 + kt) * 512);
#pragma unroll
                for (int mt = 0; mt < 4; ++mt)
                    acc[g][mt] = __builtin_amdgcn_mfma_f32_16x16x32_bf16(af[mt], bw, acc[g][mt], 0, 0, 0);
            }
        }

        // epilogue: gates + state update; h -> LDS transpose
        const char* sprb = (const char*)spr;
#pragma unroll
        for (int mt = 0; mt < 4; ++mt) {
#pragma unroll
            for (int r = 0; r < 4; ++r) {
                int b = mt * 16 + q * 4 + r;
                uint2 pv = *(const uint2*)(sprb + (size_t)b * 144 + (size_t)lm * 8);
                bf16x4 p4 = __builtin_bit_cast(bf16x4, pv);
                float zi = acc[0][mt][r] + (float)p4[0];
                float zf = acc[1][mt][r] + (float)p4[1];
                float zg = acc[2][mt][r] + (float)p4[2];
                float zo = acc[3][mt][r] + (float)p4[3];
                float ig = sigf(zi), fg = sigf(zf), gg = tanhf_f(zg), og = sigf(zo);
                float cn = fg * cst[mt][r] + ig * gg;
                cst[mt][r] = cn;
                float h = og * tanhf_f(cn);
                hprev[mt][r] = h;
                sh2[b * 24 + lm] = (bf16)h;
            }
        }

        // A-fragment-packed h store to slot s+1 via sc1 (write-through)
        bf16* hAout = hA + (size_t)(s + 1) * 102400 + (size_t)d * 51200;
#pragma unroll
        for (int it = 0; it < 2; ++it) {
            int mt = it * 2 + mtsel;
            int qp = qbase + qq;
            bf16x8 hv = *(const bf16x8*)(&sh2[(mt * 16 + lm) * 24 + qq * 8]);
            void* gp = (void*)(hAout + (size_t)(kt0 * 4 + mt) * 512 + (size_t)(qp * 16 + lm) * 8);
            store_b128_sc1(gp, __builtin_bit_cast(u32x4, hv));
        }
        asm volatile("s_waitcnt vmcnt(0)" ::: "memory");
        __hip_atomic_store(flags + bx * 32, s + 1, __ATOMIC_RELAXED, __HIP_MEMORY_SCOPE_AGENT);
    }

    // terminal barrier: all blocks consumed proj(255)
    for (;;) {
        int a  = __hip_atomic_load(flags + f1 * 32, __ATOMIC_RELAXED, __HIP_MEMORY_SCOPE_AGENT);
        int b2 = __hip_atomic_load(flags + f2 * 32, __ATOMIC_RELAXED, __HIP_MEMORY_SCOPE_AGENT);
        if (__all((a >= 256) && (b2 >= 256))) break;
    }
    asm volatile("" ::: "memory");

#pragma unroll
    for (int mt = 0; mt < 4; ++mt)
#pragma unroll
        for (int r = 0; r < 4; ++r) {
            int b = mt * 16 + q * 4 + r;
            out[((size_t)b * TDIM + 255) * 1600 + d * HDIM + jcol] = hprev[mt][r];
            out[26214400u + (size_t)b * 1600 + d * HDIM + jcol] = hprev[mt][r];
            out[26316800u + (size_t)b * 1600 + d * HDIM + jcol] = cst[mt][r];
        }
}

// ---------------------------------------------------------------------------
extern "C" void kernel_launch(void* const* d_in, const int* in_sizes, int n_in,
                              void* d_out, int out_size, void* d_ws, size_t ws_size,
                              hipStream_t stream) {
    const float* x   = (const float*)d_in[0];
    const float* mf  = (const float*)d_in[1];
    const float* mb  = (const float*)d_in[2];
    const float* Wf  = (const float*)d_in[3];
    const float* Uf  = (const float*)d_in[4];
    const float* bf_ = (const float*)d_in[5];
    const float* Wb  = (const float*)d_in[6];
    const float* Ub  = (const float*)d_in[7];
    const float* bb_ = (const float*)d_in[8];

    if (ws_size < (size_t)WS_NEED) return;

    char*  ws    = (char*)d_ws;
    bf16*  upk   = (bf16*)(ws + OFF_UPK);
    bf16*  wpk   = (bf16*)(ws + OFF_WPK);
    bf16*  projb = (bf16*)(ws + OFF_PROJB);
    bf16*  hA    = (bf16*)(ws + OFF_HA);
    int*   flags = (int*)(ws + OFF_FLAGS);
    float* out   = (float*)d_out;
    bf16*  projf = (bf16*)d_out;    // fwd proj aliased into Hcat region

    kinit<<<54, 256, 0, stream>>>((uint4*)(ws + OFF_HA), (uint4*)(ws + OFF_FLAGS));
    kpack<<<10000, 64, 0, stream>>>(Uf, Ub, upk, 25);
    kpack<<<6400, 64, 0, stream>>>(Wf, Wb, wpk, 16);
    kproj<<<10240, 256, 0, stream>>>(x, mf, mb, wpk, bf_, bb_, projf, projb);
    krecur<<<100, 64, 0, stream>>>(upk, projf, projb, hA, flags, out);
}